// Round 10
// baseline (198.281 us; speedup 1.0000x reference)
//
#include <hip/hip_runtime.h>
#include <hip/hip_bf16.h>
#include <stdint.h>

#define BATCH 16
#define CIN   512
#define COUT  512
#define HH    32
#define WW    32
#define HP    34
#define HWN   1024
#define EPS_  1e-8f

#define NTILES 72                 // 9 taps * 8 ic-chunks, BK=64
#define SLOTA_ 32768              // A: 256 rows x 128 B
#define SLOTB_ 16384              // B: 128 rows x 128 B
#define LDS_BYTES (2*SLOTA_ + 3*SLOTB_)   // 112 KB -> 1 block/CU

typedef __attribute__((ext_vector_type(8))) short bf16x8;
typedef __attribute__((ext_vector_type(4))) float f32x4;
typedef __attribute__((address_space(1))) void gvoid;
typedef __attribute__((address_space(3))) void lvoid;

// ---- workspace ----
#define XS_OFF    0
#define XS_BYTES  (BATCH*HP*HP*CIN*2)
#define WT_OFF    (XS_OFF + XS_BYTES)
#define WT_BYTES  (9*COUT*CIN*2)
#define ISG_OFF   (WT_OFF + WT_BYTES)

// ---------- fused prep (unchanged from r9) ----------
__global__ __launch_bounds__(256)
void prep_all(const float* __restrict__ x, const float* __restrict__ s,
              const float* __restrict__ w,
              __hip_bfloat16* __restrict__ xs, __hip_bfloat16* __restrict__ wt,
              float* __restrict__ isg) {
  __shared__ __align__(16) char smem[35328];
  const int bid = blockIdx.x;
  const int tid = threadIdx.x;

  if (bid < BATCH * 34) {
    unsigned short (*tile)[520] = (unsigned short (*)[520])smem;
    float* ssh = (float*)(smem + 33280);
    const int hp = bid % 34;
    const int b  = bid / 34;
    __hip_bfloat16* rowbase = xs + (((size_t)(b * HP + hp)) * HP) * CIN;

    if (hp == 0 || hp == 33) {
      for (int j = tid; j < HP * CIN / 8; j += 256)
        ((int4*)rowbase)[j] = make_int4(0, 0, 0, 0);
      return;
    }
    if (tid < 64)        ((int4*)rowbase)[tid] = make_int4(0, 0, 0, 0);
    else if (tid < 128)  ((int4*)(rowbase + 33 * CIN))[tid - 64] = make_int4(0, 0, 0, 0);

    ssh[tid]       = s[b * CIN + tid];
    ssh[256 + tid] = s[b * CIN + 256 + tid];
    __syncthreads();

    const int h = hp - 1;
    const int r = tid >> 3;
    const int c = tid & 7;
    const float* xbase = x + (size_t)b * CIN * HWN + h * WW;
#pragma unroll
    for (int p = 0; p < 16; ++p) {
      int i = p * 32 + r;
      float4 v = *(const float4*)(xbase + (size_t)i * HWN + c * 4);
      float sc = ssh[i];
#pragma unroll
      for (int j = 0; j < 4; ++j) {
        float f = ((const float*)&v)[j] * sc;
        __hip_bfloat16 hb = __float2bfloat16(f);
        tile[c * 4 + j][i] = *(unsigned short*)&hb;
      }
    }
    __syncthreads();

    const int wq = tid >> 3;
    const int i0 = (tid & 7) * 64;
    __hip_bfloat16* dst = rowbase + (wq + 1) * CIN + i0;
    const int4* src = (const int4*)&tile[wq][i0];
#pragma unroll
    for (int q = 0; q < 8; ++q)
      ((int4*)dst)[q] = src[q];
  } else {
    float* s2  = (float*)smem;
    float (*red)[4] = (float (*)[4])(smem + 32768);
    const int o = bid - BATCH * 34;
    for (int j = tid; j < BATCH * CIN; j += 256) {
      float v = s[j];
      s2[j] = v * v;
    }
    float ss[2];
#pragma unroll
    for (int u = 0; u < 2; ++u) {
      int i = tid + u * 256;
      const float* wp = w + ((size_t)o * CIN + i) * 9;
      float acc = 0.f;
#pragma unroll
      for (int k = 0; k < 9; ++k) {
        float v = wp[k];
        acc += v * v;
        wt[(size_t)k * COUT * CIN + o * CIN + i] = __float2bfloat16(v);
      }
      ss[u] = acc;
    }
    __syncthreads();
    float accb[16];
#pragma unroll
    for (int b = 0; b < 16; ++b) accb[b] = 0.f;
#pragma unroll
    for (int u = 0; u < 2; ++u) {
      int i = tid + u * 256;
      float q = ss[u];
#pragma unroll
      for (int b = 0; b < 16; ++b) accb[b] += q * s2[b * CIN + i];
    }
#pragma unroll
    for (int b = 0; b < 16; ++b) {
#pragma unroll
      for (int off = 32; off; off >>= 1) accb[b] += __shfl_xor(accb[b], off);
      if ((tid & 63) == 0) red[b][tid >> 6] = accb[b];
    }
    __syncthreads();
    if (tid < 16) {
      float tot = red[tid][0] + red[tid][1] + red[tid][2] + red[tid][3];
      isg[tid * COUT + o] = 1.0f / sqrtf(tot + EPS_);
    }
  }
}

// ---------- conv: 256x128 block, 4 waves x (128x64), counted vmcnt ----------
// LDS-traffic ratio 0.375 vs r9's 0.5: per CU-tile reads 96 KB (768 cyc) now
// BELOW the MFMA pipe time (1242 cyc) -> MFMA-bound at perfect overlap.
// A double-buffered (1-tile slack), B triple-buffered (2-tile slack).
// Ledger/tile: issue A(t+1)[8] + B(t+2)[4]; vmcnt(4) at tile end retires the
// 12 oldest (B(t+1), A(t+1)) leaving B(t+2) in flight. Never drains to 0.
__global__ __launch_bounds__(256, 1)
void conv_w(const __hip_bfloat16* __restrict__ xs,
            const __hip_bfloat16* __restrict__ wt,
            const float* __restrict__ isg,
            float* __restrict__ out) {
  extern __shared__ __align__(16) char lds[];
  char* ldsA = lds;                  // 2 x 32 KB
  char* ldsB = lds + 2 * SLOTA_;     // 3 x 16 KB

  const int bid = blockIdx.x;
  const int lin = (bid & 7) * 32 + (bid >> 3);   // XCD-contiguous, bijective (256=8*32)
  const int b  = lin >> 4;
  const int mt = (lin >> 3) & 1;     // M 256-tile
  const int nt = lin & 7;            // N 128-tile
  const int m0  = mt * 256;
  const int hw0 = nt * 128;

  const int t  = threadIdx.x;
  const int wv = t >> 6;
  const int l  = t & 63;
  const int wr = wv >> 1;            // 0..1: M half (128 rows)
  const int wc = wv & 1;             // 0..1: N half (64 cols)

  // staging bases (swizzled global source, linear LDS dest — verified r2/r8/r9)
  int baseA[8], baseB[4];
  const int swz = (l & 7) ^ (l >> 3);
#pragma unroll
  for (int q = 0; q < 8; ++q) {
    int r = (wv * 8 + q) * 8 + (l >> 3);         // 0..255
    baseA[q] = (m0 + r) * CIN + swz * 8;
  }
#pragma unroll
  for (int q = 0; q < 4; ++q) {
    int r = (wv * 4 + q) * 8 + (l >> 3);         // 0..127
    int n_abs = hw0 + r;
    int hB = n_abs >> 5, wB = n_abs & 31;
    baseB[q] = ((b * HP + hB) * HP + wB) * CIN + swz * 8;
  }

  // ds_read byte offsets (same swizzle algebra — row&7 == l&7 for all frags)
  int offA[2][8], offB[2][4];
#pragma unroll
  for (int kk = 0; kk < 2; ++kk) {
    int slot16;
#pragma unroll
    for (int mf = 0; mf < 8; ++mf) {
      slot16 = ((kk * 4) + (l >> 4)) ^ (l & 7);
      offA[kk][mf] = (wr * 128 + mf * 16 + (l & 15)) * 128 + slot16 * 16;
    }
#pragma unroll
    for (int nf = 0; nf < 4; ++nf) {
      slot16 = ((kk * 4) + (l >> 4)) ^ (l & 7);
      offB[kk][nf] = (wc * 64 + nf * 16 + (l & 15)) * 128 + slot16 * 16;
    }
  }

  f32x4 acc[8][4];
#pragma unroll
  for (int m = 0; m < 8; ++m)
#pragma unroll
    for (int n = 0; n < 4; ++n)
      acc[m][n] = (f32x4){0.f, 0.f, 0.f, 0.f};

#define STAGE_A(tt, sl)                                                     \
  {                                                                         \
    int tc_ = (tt) < NTILES ? (tt) : NTILES - 1;                            \
    int tap_ = tc_ >> 3, ic_ = tc_ & 7;                                     \
    int gA_ = tap_ * (COUT * CIN) + ic_ * 64;                               \
    char* dA_ = ldsA + (sl) * SLOTA_;                                       \
    _Pragma("unroll")                                                       \
    for (int q = 0; q < 8; ++q)                                             \
      __builtin_amdgcn_global_load_lds(                                     \
          (gvoid*)(const void*)(wt + gA_ + baseA[q]),                       \
          (lvoid*)(dA_ + (wv * 8 + q) * 1024), 16, 0, 0);                   \
  }

#define STAGE_B(tt, sl)                                                     \
  {                                                                         \
    int tc_ = (tt) < NTILES ? (tt) : NTILES - 1;                            \
    int tap_ = tc_ >> 3, ic_ = tc_ & 7;                                     \
    int kh_ = (tap_ * 11) >> 5;                                             \
    int kw_ = tap_ - kh_ * 3;                                               \
    int gB_ = (kh_ * HP + kw_) * CIN + ic_ * 64;                            \
    char* dB_ = ldsB + (sl) * SLOTB_;                                       \
    _Pragma("unroll")                                                       \
    for (int q = 0; q < 4; ++q)                                             \
      __builtin_amdgcn_global_load_lds(                                     \
          (gvoid*)(const void*)(xs + gB_ + baseB[q]),                       \
          (lvoid*)(dB_ + (wv * 4 + q) * 1024), 16, 0, 0);                   \
  }

#define KK_PHASE(kk, pA, pB)                                                \
  {                                                                         \
    bf16x8 af[8], bfr[4];                                                   \
    _Pragma("unroll")                                                       \
    for (int f = 0; f < 8; ++f) af[f]  = *(const bf16x8*)((pA) + offA[kk][f]); \
    _Pragma("unroll")                                                       \
    for (int f = 0; f < 4; ++f) bfr[f] = *(const bf16x8*)((pB) + offB[kk][f]); \
    __builtin_amdgcn_s_setprio(1);                                          \
    _Pragma("unroll")                                                       \
    for (int m = 0; m < 8; ++m)                                             \
      _Pragma("unroll")                                                     \
      for (int n = 0; n < 4; ++n)                                           \
        acc[m][n] = __builtin_amdgcn_mfma_f32_16x16x32_bf16(                \
            af[m], bfr[n], acc[m][n], 0, 0, 0);                             \
    __builtin_amdgcn_s_setprio(0);                                          \
  }

  // prologue: B(0)[4], A(0)[8], B(1)[4]; vmcnt(4) retires B(0)+A(0),
  // leaves B(1) in flight = steady-state invariant at tile-0 start.
  STAGE_B(0, 0);
  STAGE_A(0, 0);
  STAGE_B(1, 1);
  asm volatile("s_waitcnt vmcnt(4)" ::: "memory");
  __builtin_amdgcn_sched_barrier(0);
  __builtin_amdgcn_s_barrier();
  __builtin_amdgcn_sched_barrier(0);

  int bB = 0;        // B slot for tile tt  (= tt % 3)
  int sB2 = 2;       // B slot for tile tt+2
#pragma unroll 1
  for (int tt = 0; tt < NTILES; ++tt) {
    STAGE_A(tt + 1, (tt + 1) & 1);
    const char* pA = ldsA + (tt & 1) * SLOTA_;
    const char* pB = ldsB + bB * SLOTB_;
    KK_PHASE(0, pA, pB);
    STAGE_B(tt + 2, sB2);
    KK_PHASE(1, pA, pB);
    // outstanding = B(t+1)[4] + A(t+1)[8] + B(t+2)[4] = 16; vmcnt(4)
    // retires the 12 oldest -> A(t+1), B(t+1) certified; B(t+2) in flight.
    asm volatile("s_waitcnt lgkmcnt(0)" ::: "memory");
    asm volatile("s_waitcnt vmcnt(4)" ::: "memory");
    __builtin_amdgcn_sched_barrier(0);
    __builtin_amdgcn_s_barrier();
    __builtin_amdgcn_sched_barrier(0);
    bB  = (bB  == 2) ? 0 : bB + 1;
    sB2 = (sB2 == 2) ? 0 : sB2 + 1;
  }
  asm volatile("s_waitcnt vmcnt(0)" ::: "memory");

  // epilogue: C/D col=l&15 -> hw, row=(l>>4)*4+j -> o  (verified r2)
#pragma unroll
  for (int m = 0; m < 8; ++m) {
#pragma unroll
    for (int j = 0; j < 4; ++j) {
      int o = m0 + wr * 128 + m * 16 + (l >> 4) * 4 + j;
      float sg = isg[b * COUT + o];
      float* orow = out + ((size_t)(b * COUT + o)) * HWN + hw0 + wc * 64 + (l & 15);
#pragma unroll
      for (int n = 0; n < 4; ++n)
        orow[n * 16] = acc[m][n][j] * sg;
    }
  }
}

extern "C" void kernel_launch(void* const* d_in, const int* in_sizes, int n_in,
                              void* d_out, int out_size, void* d_ws, size_t ws_size,
                              hipStream_t stream) {
  const float* x = (const float*)d_in[0];
  const float* s = (const float*)d_in[1];
  const float* w = (const float*)d_in[2];
  float* out = (float*)d_out;
  char* ws = (char*)d_ws;
  __hip_bfloat16* xs  = (__hip_bfloat16*)(ws + XS_OFF);
  __hip_bfloat16* wt  = (__hip_bfloat16*)(ws + WT_OFF);
  float*          isg = (float*)(ws + ISG_OFF);

  (void)hipFuncSetAttribute((const void*)conv_w,
                            hipFuncAttributeMaxDynamicSharedMemorySize, LDS_BYTES);

  hipLaunchKernelGGL(prep_all, dim3(BATCH * 34 + COUT), dim3(256), 0, stream,
                     x, s, w, xs, wt, isg);
  hipLaunchKernelGGL(conv_w, dim3(256), dim3(256), LDS_BYTES, stream,
                     xs, wt, isg, out);
}